// Round 2
// baseline (160.379 us; speedup 1.0000x reference)
//
#include <hip/hip_runtime.h>
#include <math.h>

// Problem constants (from reference)
constexpr int NH    = 778;   // hand verts per batch
constexpr int BLK   = 128;   // threads per block (2 waves)
constexpr int NSLOT = 6;     // hand points per thread: 128*6 = 768 (+10 tail)
constexpr int CHUNK = 157;   // obj points per block chunk -> 255 chunks for V=40000

// Fused kernel:
//  - per-(batch, obj-chunk) block computes running min squared distance from
//    every hand vertex to its obj chunk using the expansion form
//    d2 = |h|^2 + |o|^2 - 2 h.o   (same numerics as the reference einsum),
//    with (-2ox,-2oy,-2oz,|o|^2) precomputed into LDS (1 ds_read_b128/point,
//    broadcast, conflict-free);
//  - atomicMin of the clamped d2 bit pattern into the global [B,NH] buffer
//    (uint ordering valid for non-negative floats);
//  - last block (device-scope ticket) reduces the 6224 mins to the 6 outputs.
__global__ __launch_bounds__(BLK) void nn_contact_kernel(
    const float* __restrict__ hand,   // [B, NH, 3]
    const float* __restrict__ obj,    // [B, V, 3]
    unsigned int* __restrict__ minb,  // [B*NH] min-d2 bits; [B*NH] = ticket
    float* __restrict__ out,          // 6 outputs
    int V, int B, int nblocks)
{
    __shared__ float4 s_obj[CHUNK + 1];
    __shared__ unsigned s_last;
    const int b   = blockIdx.y;
    const int c   = blockIdx.x;
    const int tid = threadIdx.x;
    const int j0  = c * CHUNK;
    const int cnt = min(CHUNK, V - j0);   // >= 1 by grid construction

    // stage chunk into LDS as (-2x, -2y, -2z, |o|^2)
    const float* op = obj + ((size_t)b * V + (size_t)j0) * 3;
    for (int i = tid; i < cnt; i += BLK) {
        const float x = op[3 * i + 0];
        const float y = op[3 * i + 1];
        const float z = op[3 * i + 2];
        s_obj[i] = make_float4(-2.f * x, -2.f * y, -2.f * z, x * x + y * y + z * z);
    }
    if (tid == 0) s_obj[cnt] = s_obj[0];  // pad so the j-loop can run in pairs
    __syncthreads();

    // each thread owns 6 hand points in registers
    const float* hb = hand + (size_t)b * NH * 3;
    float hx[NSLOT], hy[NSLOT], hz[NSLOT], hq[NSLOT], m[NSLOT];
#pragma unroll
    for (int s = 0; s < NSLOT; ++s) {
        const int h = tid + s * BLK;  // < 768 always
        const float x = hb[h * 3 + 0];
        const float y = hb[h * 3 + 1];
        const float z = hb[h * 3 + 2];
        hx[s] = x; hy[s] = y; hz[s] = z;
        hq[s] = x * x + y * y + z * z;
        m[s]  = 3.4e38f;
    }

    const int cnt2 = (cnt + 1) & ~1;
    for (int j = 0; j < cnt2; j += 2) {
        const float4 o0 = s_obj[j];       // broadcast b128, conflict-free
        const float4 o1 = s_obj[j + 1];
#pragma unroll
        for (int s = 0; s < NSLOT; ++s) {
            float t0 = fmaf(hx[s], o0.x, hq[s] + o0.w);
            t0 = fmaf(hy[s], o0.y, t0);
            t0 = fmaf(hz[s], o0.z, t0);
            float t1 = fmaf(hx[s], o1.x, hq[s] + o1.w);
            t1 = fmaf(hy[s], o1.y, t1);
            t1 = fmaf(hz[s], o1.z, t1);
            m[s] = fminf(fminf(t0, t1), m[s]);  // v_min3
        }
    }

#pragma unroll
    for (int s = 0; s < NSLOT; ++s) {
        const int h = tid + s * BLK;
        atomicMin(&minb[b * NH + h], __float_as_uint(fmaxf(m[s], 0.f)));
    }

    // tail: hand points 768..777 on lanes 0..9 of wave 0
    if (tid < NH - NSLOT * BLK) {
        const int h = NSLOT * BLK + tid;
        const float tx = hb[h * 3 + 0];
        const float ty = hb[h * 3 + 1];
        const float tz = hb[h * 3 + 2];
        const float tq = tx * tx + ty * ty + tz * tz;
        float tm = 3.4e38f;
        for (int j = 0; j < cnt; ++j) {
            const float4 o = s_obj[j];
            float t = fmaf(tx, o.x, tq + o.w);
            t = fmaf(ty, o.y, t);
            t = fmaf(tz, o.z, t);
            tm = fminf(tm, t);
        }
        atomicMin(&minb[b * NH + h], __float_as_uint(fmaxf(tm, 0.f)));
    }

    // ---- last-block ticket: counter initialized to 0x7F7F7F7F by the memset
    __threadfence();
    if (tid == 0) {
        const unsigned old = atomicAdd(&minb[B * NH], 1u);
        s_last = (old == 0x7F7F7F7Fu + (unsigned)(nblocks - 1)) ? 1u : 0u;
    }
    __syncthreads();
    if (!s_last) return;

    // ---- finalize (one block, 128 threads) ----
    constexpr float COLL = 0.005f;
    constexpr float CONT = 0.01f;
    const int total = B * NH;
    float sum_d = 0.f, pen_s = 0.f, att_s = 0.f;
    int pen_c = 0, att_c = 0;
    for (int i = tid; i < total; i += BLK) {
        // atomic read-back => device-coherent view of other XCDs' atomics
        const unsigned u = atomicMin(&minb[i], 0xFFFFFFFFu);
        const float d = sqrtf(__uint_as_float(u));
        sum_d += d;
        if (d < COLL) { const float t = COLL - d; pen_s += t * t; pen_c++; }
        const int n = i % NH;
        const bool isc = (n == 745) | (n == 317) | (n == 444) | (n == 556) |
                         (n == 673) | (n == 95)  | (n == 182) | (n == 234) |
                         (n == 279) | (n == 320);
        if (isc & (d > COLL) & (d < CONT)) { att_s += d * d; att_c++; }
    }

    __shared__ float rs[3][BLK];
    __shared__ int   ri[2][BLK];
    rs[0][tid] = sum_d; rs[1][tid] = pen_s; rs[2][tid] = att_s;
    ri[0][tid] = pen_c; ri[1][tid] = att_c;
    __syncthreads();
    for (int off = BLK / 2; off > 0; off >>= 1) {
        if (tid < off) {
            rs[0][tid] += rs[0][tid + off];
            rs[1][tid] += rs[1][tid + off];
            rs[2][tid] += rs[2][tid + off];
            ri[0][tid] += ri[0][tid + off];
            ri[1][tid] += ri[1][tid + off];
        }
        __syncthreads();
    }
    if (tid == 0) {
        const float pen_loss = ri[0][0] > 0 ? rs[1][0] / (float)ri[0][0] : 0.f;
        const float att_loss = ri[1][0] > 0 ? rs[2][0] / (float)ri[1][0] : 0.f;
        out[0] = 100.f * pen_loss + 10.f * att_loss;  // contact_loss
        out[1] = pen_loss;                            // pen_loss
        out[2] = att_loss;                            // att_loss
        out[3] = rs[0][0] / (float)total;             // dist_mean
        out[4] = (float)ri[1][0];                     // num_contacts
        out[5] = (float)ri[0][0];                     // num_penetrations
    }
}

extern "C" void kernel_launch(void* const* d_in, const int* in_sizes, int n_in,
                              void* d_out, int out_size, void* d_ws, size_t ws_size,
                              hipStream_t stream) {
    const float* hand = (const float*)d_in[0];  // [B, 778, 3] fp32
    const float* obj  = (const float*)d_in[1];  // [B, V, 3]   fp32
    // d_in[2] (hand_faces), d_in[3] (obj_faces): unused by the loss

    const int B = in_sizes[0] / (NH * 3);
    const int V = in_sizes[1] / (B * 3);
    const int nchunks = (V + CHUNK - 1) / CHUNK;
    const int nblocks = nchunks * B;

    unsigned int* minb = (unsigned int*)d_ws;  // [B*NH] mins + 1 ticket word

    // init mins AND ticket to 0x7F7F7F7F (~3.39e38f; > any real d2)
    hipMemsetAsync(d_ws, 0x7F, ((size_t)B * NH + 1) * sizeof(unsigned int), stream);

    dim3 grid(nchunks, B);
    nn_contact_kernel<<<grid, BLK, 0, stream>>>(hand, obj, minb, (float*)d_out,
                                                V, B, nblocks);
}